// Round 1
// baseline (502.210 us; speedup 1.0000x reference)
//
#include <hip/hip_runtime.h>

// CRF path score: out = -( sum_i logits[i, tags[i]] + sum_{i>0} T[tags[i-1], tags[i]] )
// S = 2,000,000 rows, NUM_TAGS = 50. Memory-bound gather-reduce.
// Strategy: gather 1 float per logits row (~128 MB of HBM lines vs 400 MB full
// stream), transitions table cached in LDS, hierarchical fp32 reduction,
// one atomicAdd per block.

#define NUM_TAGS 50

__global__ __launch_bounds__(256) void crf_score_kernel(
    const float* __restrict__ logits,
    const int*   __restrict__ tags,
    const float* __restrict__ trans,
    float* __restrict__ out,
    int n)
{
    __shared__ float s_trans[NUM_TAGS * NUM_TAGS];
    for (int i = threadIdx.x; i < NUM_TAGS * NUM_TAGS; i += blockDim.x)
        s_trans[i] = trans[i];
    __syncthreads();

    float acc = 0.0f;
    int idx    = blockIdx.x * blockDim.x + threadIdx.x;
    int stride = gridDim.x * blockDim.x;

    for (int i = idx; i < n; i += stride) {
        int t = tags[i];
        // emission: one element per 200-byte row (uncoalesced but line-sequential)
        acc += logits[(long long)i * NUM_TAGS + t];
        if (i + 1 < n) {
            int t2 = tags[i + 1];
            acc += s_trans[t * NUM_TAGS + t2];
        }
    }

    // wave-64 shuffle reduction
    #pragma unroll
    for (int off = 32; off > 0; off >>= 1)
        acc += __shfl_down(acc, off, 64);

    __shared__ float s_part[4];  // 256 threads = 4 waves
    int lane = threadIdx.x & 63;
    int wid  = threadIdx.x >> 6;
    if (lane == 0) s_part[wid] = acc;
    __syncthreads();

    if (wid == 0) {
        float v = (lane < 4) ? s_part[lane] : 0.0f;
        #pragma unroll
        for (int off = 2; off > 0; off >>= 1)
            v += __shfl_down(v, off, 64);
        if (lane == 0)
            atomicAdd(out, -v);  // negate: reference returns -(emit + trans)
    }
}

extern "C" void kernel_launch(void* const* d_in, const int* in_sizes, int n_in,
                              void* d_out, int out_size, void* d_ws, size_t ws_size,
                              hipStream_t stream) {
    const float* logits = (const float*)d_in[0];
    const int*   tags   = (const int*)d_in[1];
    const float* trans  = (const float*)d_in[2];
    float* out = (float*)d_out;
    int n = in_sizes[1];  // SEQ_LEN (tags element count)

    // d_out is poisoned to 0xAA before every timed launch — zero it on-stream.
    hipMemsetAsync(out, 0, sizeof(float), stream);

    const int block = 256;
    const int grid  = 2048;  // grid-stride; 2048 blocks -> 2048 atomics, ~4 elems/thread
    crf_score_kernel<<<grid, block, 0, stream>>>(logits, tags, trans, out, n);
}

// Round 2
// 492.774 us; speedup vs baseline: 1.0191x; 1.0191x over previous
//
#include <hip/hip_runtime.h>

// CRF path score: out = -( sum_i logits[i, tags[i]] + sum_{i>0} T[tags[i-1], tags[i]] )
// S = 2,000,000 rows, NUM_TAGS = 50. Memory-bound gather-reduce.
//
// R1 -> R2: chunk-of-4 per thread. One int4 tag load per thread (coalesced,
// no duplicate tags[i+1] fetch), then 4 INDEPENDENT logits gathers (one
// dependent hop tag->gather instead of four serialized loop iterations).
// Transitions (10 KB) in LDS. Hierarchical reduce -> 1 atomic per block.
// HBM floor: 2M gather lines x 64 B = 128 MB + 8 MB tags ~= 136 MB -> ~22 us.

#define NUM_TAGS 50

__global__ __launch_bounds__(256) void crf_score_kernel(
    const float* __restrict__ logits,
    const int*   __restrict__ tags,
    const float* __restrict__ trans,
    float* __restrict__ out,
    int n)
{
    __shared__ float s_trans[NUM_TAGS * NUM_TAGS];
    for (int i = threadIdx.x; i < NUM_TAGS * NUM_TAGS; i += blockDim.x)
        s_trans[i] = trans[i];
    __syncthreads();

    const int tid = blockIdx.x * blockDim.x + threadIdx.x;
    const long long i0 = (long long)tid * 4;

    float acc = 0.0f;
    if (i0 < n) {
        // n is a multiple of 4 in this problem; guard generically anyway.
        int t0, t1, t2, t3;
        if (i0 + 3 < n) {
            int4 tv = *(const int4*)(tags + i0);
            t0 = tv.x; t1 = tv.y; t2 = tv.z; t3 = tv.w;
        } else {
            t0 = tags[i0];
            t1 = (i0 + 1 < n) ? tags[i0 + 1] : 0;
            t2 = (i0 + 2 < n) ? tags[i0 + 2] : 0;
            t3 = (i0 + 3 < n) ? tags[i0 + 3] : 0;
        }

        // 4 independent emission gathers (each touches one 64B line of its row)
        const float* row = logits + i0 * NUM_TAGS;
        float e0 = row[t0];
        float e1 = (i0 + 1 < n) ? row[NUM_TAGS + t1]     : 0.0f;
        float e2 = (i0 + 2 < n) ? row[2 * NUM_TAGS + t2] : 0.0f;
        float e3 = (i0 + 3 < n) ? row[3 * NUM_TAGS + t3] : 0.0f;
        acc = e0 + e1 + e2 + e3;

        // transitions inside the chunk
        if (i0 + 1 < n) acc += s_trans[t0 * NUM_TAGS + t1];
        if (i0 + 2 < n) acc += s_trans[t1 * NUM_TAGS + t2];
        if (i0 + 3 < n) acc += s_trans[t2 * NUM_TAGS + t3];
        // boundary transition into the next chunk
        if (i0 + 4 < n) {
            int t4 = tags[i0 + 4];  // first element of next thread's line; L1/L2 hit
            acc += s_trans[t3 * NUM_TAGS + t4];
        }
    }

    // wave-64 shuffle reduction
    #pragma unroll
    for (int off = 32; off > 0; off >>= 1)
        acc += __shfl_down(acc, off, 64);

    __shared__ float s_part[4];  // 256 threads = 4 waves
    int lane = threadIdx.x & 63;
    int wid  = threadIdx.x >> 6;
    if (lane == 0) s_part[wid] = acc;
    __syncthreads();

    if (wid == 0) {
        float v = (lane < 4) ? s_part[lane] : 0.0f;
        #pragma unroll
        for (int off = 2; off > 0; off >>= 1)
            v += __shfl_down(v, off, 64);
        if (lane == 0)
            atomicAdd(out, -v);  // reference returns -(emit + trans)
    }
}

extern "C" void kernel_launch(void* const* d_in, const int* in_sizes, int n_in,
                              void* d_out, int out_size, void* d_ws, size_t ws_size,
                              hipStream_t stream) {
    const float* logits = (const float*)d_in[0];
    const int*   tags   = (const int*)d_in[1];
    const float* trans  = (const float*)d_in[2];
    float* out = (float*)d_out;
    int n = in_sizes[1];  // SEQ_LEN (tags element count)

    // d_out is poisoned to 0xAA before every timed launch — zero it on-stream.
    hipMemsetAsync(out, 0, sizeof(float), stream);

    const int block = 256;
    const int threads_needed = (n + 3) / 4;
    const int grid = (threads_needed + block - 1) / block;  // ~1954 blocks
    crf_score_kernel<<<grid, block, 0, stream>>>(logits, tags, trans, out, n);
}